// Round 1
// 155.496 us; speedup vs baseline: 1.0032x; 1.0032x over previous
//
#include <hip/hip_runtime.h>

// BiAlignLayer collapses algebraically:
//   softmax rows/cols sum to 1  =>  mean over seq of weighted_i / weighted_j
//   equal mean(i) / mean(j) exactly.  With u = mean_l(i) - mean_m(j):
//   out = 0.5 * ( relu(u@W + b) + relu(-u@W + b) )
// Stage 1: streaming reduce (i - j) over L  (~128 MB read).
//   R4: nontemporal loads 3.0 -> 4.2 TB/s. R5: 16 nt loads in flight/thread.
//   R6 (this round): break the 16-wave lockstep. 1024-thread blocks fit only
//   1 block/CU (VGPR cap) -> 2 dispatch rounds of burst/drain/tail with the
//   HBM queue emptying at every block boundary. Same 16-deep nt bursts, but
//   256-thread blocks x 4 blocks/CU x 8 rounds: blocks retire asynchronously,
//   tails overlap other blocks' bursts, load issue stays continuous.
// Stage 2: [B,D] x [D,NN] matvec + bias + dual relu (SPLIT=64 partials now)

#define BB 32
#define LL 1024
#define DD 512
#define NNN 512
#define SPLIT 64
#define ROWS (LL / SPLIT)          // 16 rows per chunk
#define NVEC (ROWS * DD / 4)       // 2048 float4 per chunk per stream
#define T1 256                     // stage1 block size (4 waves)
#define NWIN (NVEC / T1)           // 8 windows per stream

typedef float f4 __attribute__((ext_vector_type(4)));

__global__ __launch_bounds__(T1, 4) void bialign_stage1(
    const float* __restrict__ gi, const float* __restrict__ gj,
    float* __restrict__ part) {
    const int blk = blockIdx.x;            // b*SPLIT + s
    const int b = blk >> 6;                // / SPLIT
    const int s = blk & (SPLIT - 1);
    const size_t base = (size_t)b * LL * DD + (size_t)s * ROWS * DD;
    const f4* i4 = (const f4*)(gi + base);
    const f4* j4 = (const f4*)(gj + base);
    const int t = threadIdx.x;

    // All 16 independent nt loads issued before any use: 256 B payload
    // = 64 VGPRs, allowed by the 128-VGPR cap (launch_bounds 256,4).
    f4 a[NWIN], c[NWIN];
    #pragma unroll
    for (int w = 0; w < NWIN; ++w) {
        a[w] = __builtin_nontemporal_load(i4 + (size_t)w * T1 + t);
        c[w] = __builtin_nontemporal_load(j4 + (size_t)w * T1 + t);
    }

    // Window stride = T1 f4 = 1024 floats == 0 mod 512 -> each thread's
    // d-phase is constant: phase(t) = (4t) mod 512; 2 phase-groups (t>>7).
    f4 acc0 = 0.f, acc1 = 0.f, acc2 = 0.f, acc3 = 0.f;
    #pragma unroll
    for (int w = 0; w < NWIN; w += 4) {
        acc0 += a[w + 0] - c[w + 0];
        acc1 += a[w + 1] - c[w + 1];
        acc2 += a[w + 2] - c[w + 2];
        acc3 += a[w + 3] - c[w + 3];
    }
    acc0 += acc1;
    acc2 += acc3;
    acc0 += acc2;

    // 2 phase-groups of 128 threads each -> LDS [2][512] floats (4 KB)
    __shared__ float sm[2 * DD];
    f4* sm4 = (f4*)sm;
    sm4[(t >> 7) * 128 + (t & 127)] = acc0;     // group g, slot p = t&127
    __syncthreads();
    if (t < 128) {
        f4 s0 = sm4[t] + sm4[128 + t];
        ((f4*)(part + (size_t)blk * DD))[t] = s0;
    }
}

// Stage 2: grid (B, 4) blocks of 256. Block (b, ns) computes out[b, ns*128 .. +127].
// Threads t<128 accumulate d=[0,256) for col ns*128+t; t>=128 accumulate d=[256,512)
// for col ns*128+(t-128); combine in LDS.
__global__ __launch_bounds__(256) void bialign_stage2(
    const float* __restrict__ part, const float* __restrict__ W,
    const float* __restrict__ bias, float* __restrict__ out) {
    const int b = blockIdx.x;
    const int ns = blockIdx.y;
    const int t = threadIdx.x;              // 256

    __shared__ float u[DD];
    __shared__ float psum[256];
    // u[d] = (1/L) * sum over SPLIT partials
    for (int d = t; d < DD; d += 256) {
        const float* p = part + (size_t)b * SPLIT * DD + d;
        float sum = 0.f;
        #pragma unroll
        for (int k = 0; k < SPLIT; ++k) sum += p[(size_t)k * DD];
        u[d] = sum * (1.0f / (float)LL);
    }
    __syncthreads();

    const int col = ns * 128 + (t & 127);
    const int d0 = (t >> 7) * 256;          // 0 or 256
    float acc = 0.f;
    #pragma unroll 8
    for (int d = 0; d < 256; ++d) {
        acc = fmaf(u[d0 + d], W[(size_t)(d0 + d) * NNN + col], acc);
    }
    psum[t] = acc;
    __syncthreads();
    if (t < 128) {
        const float dot = psum[t] + psum[t + 128];
        const float bb = bias[col];
        const float r = 0.5f * (fmaxf(dot + bb, 0.f) + fmaxf(bb - dot, 0.f));
        out[(size_t)b * NNN + col] = r;
    }
}

extern "C" void kernel_launch(void* const* d_in, const int* in_sizes, int n_in,
                              void* d_out, int out_size, void* d_ws, size_t ws_size,
                              hipStream_t stream) {
    const float* gi   = (const float*)d_in[0];   // [B, L, D]
    const float* gj   = (const float*)d_in[1];   // [B, L, D]
    const float* W    = (const float*)d_in[2];   // [D, NN]
    const float* bias = (const float*)d_in[3];   // [NN]
    float* out = (float*)d_out;                  // [B, NN]
    float* part = (float*)d_ws;                  // B*SPLIT*D floats = 4 MB

    bialign_stage1<<<BB * SPLIT, T1, 0, stream>>>(gi, gj, part);
    bialign_stage2<<<dim3(BB, 4), 256, 0, stream>>>(part, W, bias, out);
}